// Round 3
// baseline (2254.511 us; speedup 1.0000x reference)
//
#include <hip/hip_runtime.h>

#define T_STEPS 60
#define WARMUP  29
#define HID     32
#define CT      240   // 4 * T_STEPS

__device__ __forceinline__ float fexp2(float x) { return __builtin_amdgcn_exp2f(x); }
__device__ __forceinline__ float frcp(float x)  { return __builtin_amdgcn_rcpf(x); }
__device__ __forceinline__ float sigmoid_f(float x) {
    return frcp(1.0f + fexp2(-1.4426950408889634f * x));
}
__device__ __forceinline__ float tanh_f(float x) {
    float e = fexp2(2.8853900817779268f * x);
    return 1.0f - 2.0f * frcp(e + 1.0f);
}

// Force a value into an arch VGPR at this program point. Round-2 lesson:
// preheader-only PIN is useless (allocator moves values to AGPRs right after
// and pays a copy per use per step). PIN_ALL() is therefore executed INSIDE
// the time loop: with every weight touched in a VGPR each iteration, keeping
// them AGPR-resident would cost 90 copies/iter -> allocator keeps them in
// arch VGPRs. Live set is ~130 regs, well under the (256,3) cap of ~170.
#define PIN(x) asm("" : "+v"(x))
#define PIN_ALL() do {                                                         \
    _Pragma("unroll") for (int k_ = 0; k_ < HID; ++k_) { PIN(wa[k_]); PIN(wb[k_]); } \
    _Pragma("unroll") for (int c_ = 0; c_ < 4; ++c_) { PIN(wi1[c_]); PIN(wi2[c_]); PIN(wi3[c_]); } \
    PIN(b1); PIN(b2); PIN(b3); PIN(b4);                                        \
} while (0)

// Broadcast lane K within each 32-lane group (immediate pattern, no index reg).
template<int K>
__device__ __forceinline__ float swz(float x) {
    return __int_as_float(__builtin_amdgcn_ds_swizzle(__float_as_int(x), (K << 5)));
}
// Full-wave gather: result = src value of lane (idx>>2). idx precomputed once.
__device__ __forceinline__ float bperm(int idx, float x) {
    return __int_as_float(__builtin_amdgcn_ds_bpermute(idx, __float_as_int(x)));
}

#define GATHER32(v, x) do { \
    v[0]  = swz<0>(x);  v[1]  = swz<1>(x);  v[2]  = swz<2>(x);  v[3]  = swz<3>(x);  \
    v[4]  = swz<4>(x);  v[5]  = swz<5>(x);  v[6]  = swz<6>(x);  v[7]  = swz<7>(x);  \
    v[8]  = swz<8>(x);  v[9]  = swz<9>(x);  v[10] = swz<10>(x); v[11] = swz<11>(x); \
    v[12] = swz<12>(x); v[13] = swz<13>(x); v[14] = swz<14>(x); v[15] = swz<15>(x); \
    v[16] = swz<16>(x); v[17] = swz<17>(x); v[18] = swz<18>(x); v[19] = swz<19>(x); \
    v[20] = swz<20>(x); v[21] = swz<21>(x); v[22] = swz<22>(x); v[23] = swz<23>(x); \
    v[24] = swz<24>(x); v[25] = swz<25>(x); v[26] = swz<26>(x); v[27] = swz<27>(x); \
    v[28] = swz<28>(x); v[29] = swz<29>(x); v[30] = swz<30>(x); v[31] = swz<31>(x); \
} while (0)

// One GRU step, 64 lanes = 1 batch. Low half (hb=0), lane j:
//   acc1 = gr chain (bgr, ih wir, hh whr)   acc2 = gz chain (bgz, ih wiz, hh whz)
// High half (hb=1), lane 32+j:
//   acc1 = gnh chain (bgnh, 0*ih, hh whn)   acc3 = gni chain (bgni, ih win)
//   proj (after h update): og = bl + sum wlin*v  (wb holds wlin in high half)
// Zero-weight fma padding is exact: fma(0,u,a)==a for finite u.
// All chain orders bitwise-match the previous passing kernel.
#define BODY() do {                                                            \
    PIN_ALL();                                                                 \
    float a1 = b1, a2 = b2, a3 = b3;                                           \
    a1 = __builtin_fmaf(wi1[0], u0, a1); a2 = __builtin_fmaf(wi2[0], u0, a2); a3 = __builtin_fmaf(wi3[0], u0, a3); \
    a1 = __builtin_fmaf(wi1[1], u1, a1); a2 = __builtin_fmaf(wi2[1], u1, a2); a3 = __builtin_fmaf(wi3[1], u1, a3); \
    a1 = __builtin_fmaf(wi1[2], u2, a1); a2 = __builtin_fmaf(wi2[2], u2, a2); a3 = __builtin_fmaf(wi3[2], u2, a3); \
    a1 = __builtin_fmaf(wi1[3], u3, a1); a2 = __builtin_fmaf(wi2[3], u3, a2); a3 = __builtin_fmaf(wi3[3], u3, a3); \
    _Pragma("unroll")                                                          \
    for (int k = 0; k < HID; ++k) {                                            \
        a1 = __builtin_fmaf(wa[k], v[k], a1);                                  \
        a2 = __builtin_fmaf(wb[k], v[k], a2);                                  \
    }                                                                          \
    float gnhx = bperm(idxHi, a1);    /* low lane j <- high lane 32+j's gnh */ \
    float gnix = bperm(idxHi, a3);    /* low lane j <- high lane 32+j's gni */ \
    float r = sigmoid_f(a1);                                                   \
    float z = sigmoid_f(a2);                                                   \
    float n = tanh_f(__builtin_fmaf(r, gnhx, gnix));                           \
    x = __builtin_fmaf(z, x - n, n);  /* valid in low half only */             \
    float xx = bperm(idxLo, x);       /* every lane reads low lane j */        \
    GATHER32(v, xx);                  /* v[] = h_new in all 64 lanes */        \
    og = b4;                                                                   \
    _Pragma("unroll")                                                          \
    for (int k = 0; k < HID; ++k) og = __builtin_fmaf(wb[k], v[k], og);        \
} while (0)

// NOTE deliberately NO __restrict__/const on weight pointers or out/h28out:
// stores each step + no restrict => compiler cannot legally re-load weights
// inside the loop (anti-rematerialization insurance, kept from round 2).
__global__ __launch_bounds__(256, 3) void gru_fused(
    const float* __restrict__ in,
    const float* w_ih,  const float* w_hh,
    const float* b_ih,  const float* b_hh,
    const float* w_lin, const float* b_lin,
    float* out, float* h28out, int B)
{
    const int lane = threadIdx.x & 63;
    const int j    = lane & 31;
    const int hb   = lane >> 5;              // 0 = r/z half, 1 = n/proj half
    const int wv   = threadIdx.x >> 6;
    const int b    = blockIdx.x * 4 + wv;    // one batch per wave

    // ---- one-time weight load ----
    float wa[HID], wb[HID], wi1[4], wi2[4], wi3[4];
    {
        const float4* pa = (const float4*)(w_hh + (size_t)(hb ? (2 * HID + j) : j) * HID);
        const float4* pb = hb ? (const float4*)(w_lin + (size_t)(j & 3) * HID)
                              : (const float4*)(w_hh + (size_t)(HID + j) * HID);
#pragma unroll
        for (int q = 0; q < 8; ++q) {
            float4 A = pa[q];
            wa[4*q] = A.x; wa[4*q+1] = A.y; wa[4*q+2] = A.z; wa[4*q+3] = A.w;
            float4 Bv = pb[q];
            wb[4*q] = Bv.x; wb[4*q+1] = Bv.y; wb[4*q+2] = Bv.z; wb[4*q+3] = Bv.w;
        }
        float4 r1 = ((const float4*)w_ih)[j];
        float4 r2 = ((const float4*)w_ih)[HID + j];
        float4 r3 = ((const float4*)w_ih)[2 * HID + j];
        wi1[0] = hb ? 0.0f : r1.x; wi1[1] = hb ? 0.0f : r1.y;
        wi1[2] = hb ? 0.0f : r1.z; wi1[3] = hb ? 0.0f : r1.w;
        wi2[0] = hb ? 0.0f : r2.x; wi2[1] = hb ? 0.0f : r2.y;
        wi2[2] = hb ? 0.0f : r2.z; wi2[3] = hb ? 0.0f : r2.w;
        wi3[0] = hb ? r3.x : 0.0f; wi3[1] = hb ? r3.y : 0.0f;
        wi3[2] = hb ? r3.z : 0.0f; wi3[3] = hb ? r3.w : 0.0f;
    }
    float b1 = hb ? b_hh[2 * HID + j] : (b_ih[j] + b_hh[j]);
    float b2 = hb ? 0.0f              : (b_ih[HID + j] + b_hh[HID + j]);
    float b3 = hb ? b_ih[2 * HID + j] : 0.0f;
    float b4 = hb ? b_lin[j & 3]      : 0.0f;

    const int idxLo = j << 2;                // read low lane j (full-wave bperm)
    const int idxHi = (j + 32) << 2;         // read high lane 32+j
    const bool doO   = (hb == 1) && (j < 4); // lanes 32..35 own o_0..o_3
    const bool doH28 = (hb == 0);

    float v[HID];
    float u0, u1, u2, u3, x = 0.0f, og = 0.0f;
#pragma unroll
    for (int k = 0; k < HID; ++k) v[k] = 0.0f;   // h0 = 0

    const float* pin  = in  + (size_t)b * CT;                 // [4][60] row
    float*       pout = out + (size_t)b * CT + j * T_STEPS;   // valid when doO

    // Phase 1: warmup — inputs from ground truth, next-step loads prefetched
    u0 = pin[0]; u1 = pin[60]; u2 = pin[120]; u3 = pin[180];
#pragma unroll 1
    for (int t = 0; t < WARMUP; ++t) {
        float n0 = 0.0f, n1 = 0.0f, n2 = 0.0f, n3 = 0.0f;
        if (t + 1 < WARMUP) {
            n0 = pin[t + 1]; n1 = pin[61 + t]; n2 = pin[121 + t]; n3 = pin[181 + t];
        }
        BODY();
        if (doO) pout[t] = og;
        u0 = n0; u1 = n1; u2 = n2; u3 = n3;
    }

    // h after step t == WARMUP-1 lives in the low half (lane j = unit j)
    if (doH28) h28out[(size_t)b * HID + j] = x;

    // Phase 2: feedback — u = broadcast of og (high lanes 32..35 hold o_0..3)
#pragma unroll 1
    for (int t = WARMUP; t < T_STEPS; ++t) {
        float oo = bperm(idxHi, og);         // lane c (both halves) -> o_{c&3}
        u0 = swz<0>(oo); u1 = swz<1>(oo); u2 = swz<2>(oo); u3 = swz<3>(oo);
        BODY();
        if (doO) pout[t] = og;
    }
}

extern "C" void kernel_launch(void* const* d_in, const int* in_sizes, int n_in,
                              void* d_out, int out_size, void* d_ws, size_t ws_size,
                              hipStream_t stream) {
    const float* input = (const float*)d_in[0];
    float* w_ih  = (float*)d_in[1];
    float* w_hh  = (float*)d_in[2];
    float* b_ih  = (float*)d_in[3];
    float* b_hh  = (float*)d_in[4];
    float* w_lin = (float*)d_in[5];
    float* b_lin = (float*)d_in[6];

    const int B = in_sizes[0] / CT;          // 131072
    float* out = (float*)d_out;              // [B][240]
    float* h28 = out + (size_t)B * CT;       // [B][32]
    (void)d_ws; (void)ws_size;

    hipLaunchKernelGGL(gru_fused, dim3(B / 4), dim3(256), 0, stream,
                       input, w_ih, w_hh, b_ih, b_hh, w_lin, b_lin, out, h28, B);
}

// Round 5
// 1594.264 us; speedup vs baseline: 1.4141x; 1.4141x over previous
//
#include <hip/hip_runtime.h>

#define T_STEPS 60
#define WARMUP  29
#define HID     32
#define CT      240   // 4 * T_STEPS

__device__ __forceinline__ float fexp2(float x) { return __builtin_amdgcn_exp2f(x); }
__device__ __forceinline__ float frcp(float x)  { return __builtin_amdgcn_rcpf(x); }
__device__ __forceinline__ float sigmoid_f(float x) {
    return frcp(1.0f + fexp2(-1.4426950408889634f * x));
}
__device__ __forceinline__ float tanh_f(float x) {
    float e = fexp2(2.8853900817779268f * x);
    return 1.0f - 2.0f * frcp(e + 1.0f);
}

// Broadcast the value held by lane K of each 32-lane half to all lanes of that
// half. ds_swizzle BitMode: src = ((lane & and) | or) ^ xor with and=0, or=K,
// xor=0 -> offset = K<<5. Register-only, no LDS storage, bit-exact move.
template<int K>
__device__ __forceinline__ float bcast(float x) {
    return __int_as_float(__builtin_amdgcn_ds_swizzle(__float_as_int(x), (K << 5)));
}

#define GATHER32(v, x) do { \
    v[0]  = bcast<0>(x);  v[1]  = bcast<1>(x);  v[2]  = bcast<2>(x);  v[3]  = bcast<3>(x);  \
    v[4]  = bcast<4>(x);  v[5]  = bcast<5>(x);  v[6]  = bcast<6>(x);  v[7]  = bcast<7>(x);  \
    v[8]  = bcast<8>(x);  v[9]  = bcast<9>(x);  v[10] = bcast<10>(x); v[11] = bcast<11>(x); \
    v[12] = bcast<12>(x); v[13] = bcast<13>(x); v[14] = bcast<14>(x); v[15] = bcast<15>(x); \
    v[16] = bcast<16>(x); v[17] = bcast<17>(x); v[18] = bcast<18>(x); v[19] = bcast<19>(x); \
    v[20] = bcast<20>(x); v[21] = bcast<21>(x); v[22] = bcast<22>(x); v[23] = bcast<23>(x); \
    v[24] = bcast<24>(x); v[25] = bcast<25>(x); v[26] = bcast<26>(x); v[27] = bcast<27>(x); \
    v[28] = bcast<28>(x); v[29] = bcast<29>(x); v[30] = bcast<30>(x); v[31] = bcast<31>(x); \
} while (0)

// One GRU step. Accumulation order bitwise-matches the original passing
// kernel: bias add first, then k=0..3 over w_ih, then k=0..31 over w_hh, each
// gate a single sequential fma chain; projection is the same sequential chain.
#define GRU_STEP() do {                                                        \
    float gr = bgr, gz = bgz, gni = bgni, gnh = bgnh;                          \
    _Pragma("unroll")                                                          \
    for (int c = 0; c < 4; ++c) {                                              \
        gr  = __builtin_fmaf(wir[c], u[c], gr);                                \
        gz  = __builtin_fmaf(wiz[c], u[c], gz);                                \
        gni = __builtin_fmaf(win[c], u[c], gni);                               \
    }                                                                          \
    _Pragma("unroll")                                                          \
    for (int k = 0; k < HID; ++k) {                                            \
        gr  = __builtin_fmaf(whr[k], v[k], gr);                                \
        gz  = __builtin_fmaf(whz[k], v[k], gz);                                \
        gnh = __builtin_fmaf(whn[k], v[k], gnh);                               \
    }                                                                          \
    float r = sigmoid_f(gr);                                                   \
    float z = sigmoid_f(gz);                                                   \
    float n = tanh_f(__builtin_fmaf(r, gnh, gni));                             \
    x = __builtin_fmaf(z, x - n, n);                                           \
    GATHER32(v, x);                                                            \
    o = bl;                                                                    \
    _Pragma("unroll")                                                          \
    for (int k = 0; k < HID; ++k) o = __builtin_fmaf(wlr[k], v[k], o);         \
} while (0)

// Lane j of each 32-lane half owns hidden unit j of one batch element.
//
// amdgpu_waves_per_eu(2,2): rounds 1-3 showed the backend targets MAX
// occupancy (arch VGPR budgets of 96/84/68 = 5-8 waves/EU) and parks the
// ~145 loop-invariant weights in AGPRs with per-use copies (~360 extra
// VALU cycles/step — the measured 2x bloat). Capping max waves/EU at 2
// gives the allocator a 256-reg arch budget; the ~200 live values then fit
// in arch VGPRs with no shuttling.
//
// NOTE deliberately NO __restrict__/const on weight pointers or out/h28out:
// stores to out happen every step, so without restrict the compiler cannot
// legally re-load weights inside the loop — they must stay register-resident.
__global__ __launch_bounds__(256)
__attribute__((amdgpu_waves_per_eu(2, 2)))
void gru_fused(
    const float* __restrict__ in,
    const float* w_ih,  const float* w_hh,
    const float* b_ih,  const float* b_hh,
    const float* w_lin, const float* b_lin,
    float* out, float* h28out, int B)
{
    const int lane = threadIdx.x & 63;
    const int j    = lane & 31;                 // hidden unit owned by this lane
    const int wv   = threadIdx.x >> 6;          // wave index in block
    const int s    = lane >> 5;                 // batch slot within wave
    const int b    = blockIdx.x * 8 + wv * 2 + s;

    // ---- one-time: load resident weights (rows of this lane's hidden unit) ----
    float whr[HID], whz[HID], whn[HID], wlr[HID];
    float wir[4], wiz[4], win[4];
    {
        const float4* pr = (const float4*)(w_hh + (size_t)j * HID);
        const float4* pz = (const float4*)(w_hh + (size_t)(HID + j) * HID);
        const float4* pn = (const float4*)(w_hh + (size_t)(2 * HID + j) * HID);
        const float4* pl = (const float4*)(w_lin + (size_t)(j & 3) * HID);
#pragma unroll
        for (int q = 0; q < 8; ++q) {
            float4 a = pr[q];
            whr[4*q] = a.x; whr[4*q+1] = a.y; whr[4*q+2] = a.z; whr[4*q+3] = a.w;
            float4 c = pz[q];
            whz[4*q] = c.x; whz[4*q+1] = c.y; whz[4*q+2] = c.z; whz[4*q+3] = c.w;
            float4 d = pn[q];
            whn[4*q] = d.x; whn[4*q+1] = d.y; whn[4*q+2] = d.z; whn[4*q+3] = d.w;
            float4 e = pl[q];
            wlr[4*q] = e.x; wlr[4*q+1] = e.y; wlr[4*q+2] = e.z; wlr[4*q+3] = e.w;
        }
        float4 a = ((const float4*)w_ih)[j];
        wir[0] = a.x; wir[1] = a.y; wir[2] = a.z; wir[3] = a.w;
        float4 c = ((const float4*)w_ih)[HID + j];
        wiz[0] = c.x; wiz[1] = c.y; wiz[2] = c.z; wiz[3] = c.w;
        float4 d = ((const float4*)w_ih)[2 * HID + j];
        win[0] = d.x; win[1] = d.y; win[2] = d.z; win[3] = d.w;
    }
    const float bgr  = b_ih[j]           + b_hh[j];
    const float bgz  = b_ih[HID + j]     + b_hh[HID + j];
    const float bgni = b_ih[2 * HID + j];
    const float bgnh = b_hh[2 * HID + j];
    const float bl   = b_lin[j & 3];

    float v[HID], u[4];
    float x = 0.0f, o = 0.0f;
#pragma unroll
    for (int k = 0; k < HID; ++k) v[k] = 0.0f;   // h0 = 0

    const float* pin  = in  + (size_t)b * CT;                    // [4][60] row
    float*       pout = out + (size_t)b * CT + (j & 3) * T_STEPS; // used when j<4

    // Phase 1: warmup — input from ground truth
#pragma unroll 1
    for (int t = 0; t < WARMUP; ++t) {
        u[0] = pin[t];
        u[1] = pin[60 + t];
        u[2] = pin[120 + t];
        u[3] = pin[180 + t];
        GRU_STEP();
        if (j < 4) pout[t] = o;
    }

    // h after step t == WARMUP-1
    h28out[(size_t)b * HID + j] = x;

    // Phase 2: feedback — input is previous step's projection (lanes 0..3 of
    // each half hold o_0..o_3; broadcast them, bit-exact)
#pragma unroll 1
    for (int t = WARMUP; t < T_STEPS; ++t) {
        u[0] = bcast<0>(o);
        u[1] = bcast<1>(o);
        u[2] = bcast<2>(o);
        u[3] = bcast<3>(o);
        GRU_STEP();
        if (j < 4) pout[t] = o;
    }
}

extern "C" void kernel_launch(void* const* d_in, const int* in_sizes, int n_in,
                              void* d_out, int out_size, void* d_ws, size_t ws_size,
                              hipStream_t stream) {
    const float* input = (const float*)d_in[0];
    float* w_ih  = (float*)d_in[1];
    float* w_hh  = (float*)d_in[2];
    float* b_ih  = (float*)d_in[3];
    float* b_hh  = (float*)d_in[4];
    float* w_lin = (float*)d_in[5];
    float* b_lin = (float*)d_in[6];

    const int B = in_sizes[0] / CT;          // 131072
    float* out = (float*)d_out;              // [B][240]
    float* h28 = out + (size_t)B * CT;       // [B][32]
    (void)d_ws; (void)ws_size;

    hipLaunchKernelGGL(gru_fused, dim3(B / 8), dim3(256), 0, stream,
                       input, w_ih, w_hh, b_ih, b_hh, w_lin, b_lin, out, h28, B);
}